// Round 4
// baseline (653.583 us; speedup 1.0000x reference)
//
#include <hip/hip_runtime.h>
#include <hip/hip_bf16.h>

// ---------------------------------------------------------------------------
// AttentionBlock: GroupNorm -> q,k,v 1x1 conv -> softmax(-128 * q^T k) -> PV
//                 + conv1x1(x, Wo)
// B=8, C=256, HW=4096, 32 groups. fp32 in/out.
// Scores need bf16x2 split (3-MFMA) path; V/PV/out-proj plain bf16.
// flash4: 1 block/CU, 8 waves, 128 i-rows. S j-split (wave = 16 j x 32 i,
//         K-read redundancy 2x not 4x). Cross-wave max exchange via LDS.
//         PV c-split 8-way, V from global regs. lgkm-only mid barriers so
//         K prefetch stays in flight. No LDS state crosses an iteration.
// ---------------------------------------------------------------------------

typedef __attribute__((ext_vector_type(8))) short bf16x8;
typedef __attribute__((ext_vector_type(4))) short s16x4;
typedef __attribute__((ext_vector_type(8))) short s16x8;
typedef __attribute__((ext_vector_type(4))) float f32x4;

#define MFMA16(a, b, c) __builtin_amdgcn_mfma_f32_16x16x32_bf16((a), (b), (c), 0, 0, 0)

// -0.5 * C * log2(e): fold attention scale (and exp->exp2) into q.
#define SCALE_Q (-184.66496523378734f)

__device__ __forceinline__ short f2bf(float f) {
  unsigned int u = __builtin_bit_cast(unsigned int, f);
  u = (u + 0x7FFFu + ((u >> 16) & 1u)) >> 16;
  return (short)(unsigned short)u;
}
__device__ __forceinline__ float bf2f(short h) {
  unsigned int u = ((unsigned int)(unsigned short)h) << 16;
  return __builtin_bit_cast(float, u);
}
__device__ __forceinline__ void async16(void* lds, const void* g) {
  __builtin_amdgcn_global_load_lds(
      (const __attribute__((address_space(1))) unsigned int*)g,
      (__attribute__((address_space(3))) unsigned int*)lds, 16, 0, 0);
}
// P-write visibility barrier: drain own LDS ops, arrive, block reordering.
__device__ __forceinline__ void lgkm_barrier() {
  asm volatile("s_waitcnt lgkmcnt(0)" ::: "memory");
  __builtin_amdgcn_s_barrier();
  __builtin_amdgcn_sched_barrier(0);
}

// --------------------------- W -> hi/lo bf16 split -------------------------
__global__ void wsplit_k(const float* __restrict__ Wq, const float* __restrict__ Wk,
                         const float* __restrict__ Wv, const float* __restrict__ Wo,
                         short* __restrict__ whi, short* __restrict__ wlo) {
  int idx = blockIdx.x * 256 + threadIdx.x;   // 0 .. 4*65536-1
  int m = idx >> 16;
  int e = idx & 65535;
  const float* W = (m == 0) ? Wq : (m == 1) ? Wk : (m == 2) ? Wv : Wo;
  float v = W[e];
  short h = f2bf(v);
  whi[idx] = h;
  wlo[idx] = f2bf(v - bf2f(h));
}

// --------------------------- GroupNorm stats -------------------------------
__global__ void gn_stats_k(const float* __restrict__ x, float* __restrict__ stats) {
  int bg = blockIdx.x;          // b*32 + g, contiguous 32768 floats
  int tid = threadIdx.x;
  const float* p = x + (size_t)bg * 32768;
  float s = 0.f, sq = 0.f;
  for (int it = 0; it < 32; ++it) {
    f32x4 v = *(const f32x4*)(p + (size_t)(it * 256 + tid) * 4);
    s += v[0] + v[1] + v[2] + v[3];
    sq += v[0] * v[0] + v[1] * v[1] + v[2] * v[2] + v[3] * v[3];
  }
#pragma unroll
  for (int off = 1; off < 64; off <<= 1) {
    s += __shfl_xor(s, off);
    sq += __shfl_xor(sq, off);
  }
  __shared__ float ls[4], lq[4];
  int w = tid >> 6;
  if ((tid & 63) == 0) { ls[w] = s; lq[w] = sq; }
  __syncthreads();
  if (tid == 0) {
    float S = ls[0] + ls[1] + ls[2] + ls[3];
    float Q = lq[0] + lq[1] + lq[2] + lq[3];
    float mean = S * (1.f / 32768.f);
    float var = Q * (1.f / 32768.f) - mean * mean;
    stats[bg * 2] = mean;
    stats[bg * 2 + 1] = rsqrtf(var + 1e-5f);
  }
}

// ------------------- GroupNorm apply + transpose + split -------------------
// x[b][c][i] fp32 -> hnT[b][i][c] bf16 hi/lo  (c contiguous)
__global__ void gn_apply_k(const float* __restrict__ x, const float* __restrict__ gamma,
                           const float* __restrict__ beta, const float* __restrict__ stats,
                           short* __restrict__ hn_hi, short* __restrict__ hn_lo) {
  __shared__ float tile[64 * 68];
  int tid = threadIdx.x;
  int b = blockIdx.z, c0 = blockIdx.y * 64, i0 = blockIdx.x * 64;
  int cc = tid >> 4, ich = tid & 15;
#pragma unroll
  for (int it = 0; it < 4; ++it) {
    int c = c0 + cc + it * 16;
    f32x4 vx = *(const f32x4*)(x + ((size_t)(b * 256 + c)) * 4096 + i0 + ich * 4);
    float mean = stats[(b * 32 + (c >> 3)) * 2];
    float rstd = stats[(b * 32 + (c >> 3)) * 2 + 1];
    float ga = gamma[c] * rstd;
    float be = beta[c] - mean * ga;
    f32x4 h = {vx[0] * ga + be, vx[1] * ga + be, vx[2] * ga + be, vx[3] * ga + be};
    *(f32x4*)(&tile[(cc + it * 16) * 68 + ich * 4]) = h;
  }
  __syncthreads();
  int il = tid >> 2, ch = tid & 3;
  s16x8 hv0, hv1, lv0, lv1;
#pragma unroll
  for (int u = 0; u < 16; ++u) {
    float vv = tile[(ch * 16 + u) * 68 + il];
    short h = f2bf(vv);
    short lo = f2bf(vv - bf2f(h));
    if (u < 8) { hv0[u] = h; lv0[u] = lo; } else { hv1[u - 8] = h; lv1[u - 8] = lo; }
  }
  size_t ro = ((size_t)(b * 4096 + i0 + il)) * 256 + c0 + ch * 16;
  *(s16x8*)(hn_hi + ro) = hv0;
  *(s16x8*)(hn_hi + ro + 8) = hv1;
  *(s16x8*)(hn_lo + ro) = lv0;
  *(s16x8*)(hn_lo + ro + 8) = lv1;
}

// ----------------------- Q/K projection (3-term split) ---------------------
__global__ __launch_bounds__(256) void proj_qk_k(
    const short* __restrict__ hn_hi, const short* __restrict__ hn_lo,
    const short* __restrict__ whi, const short* __restrict__ wlo,
    const float* __restrict__ bq, const float* __restrict__ bk,
    short* __restrict__ q_hi, short* __restrict__ q_lo,
    short* __restrict__ k_hi, short* __restrict__ k_lo) {
  int tid = threadIdx.x, w = tid >> 6, lane = tid & 63, l4 = lane & 15, g = lane >> 4;
  int iblk = blockIdx.x, y = blockIdx.y, b = blockIdx.z;
  const short* wh = whi + y * 65536;
  const short* wl = wlo + y * 65536;
  const float* bias = y ? bk : bq;
  short* ohi = (y ? k_hi : q_hi) + (size_t)b * 1048576;
  short* olo = (y ? k_lo : q_lo) + (size_t)b * 1048576;
  float scale = y ? 1.0f : SCALE_Q;
  int arow = iblk * 64 + w * 16 + l4;
  const short* ha = hn_hi + ((size_t)(b * 4096 + arow)) * 256 + g * 8;
  const short* la = hn_lo + ((size_t)(b * 4096 + arow)) * 256 + g * 8;
  f32x4 acc[16];
#pragma unroll
  for (int i = 0; i < 16; ++i) acc[i] = (f32x4){0.f, 0.f, 0.f, 0.f};
  for (int ks = 0; ks < 8; ++ks) {
    bf16x8 ah = *(const bf16x8*)(ha + ks * 32);
    bf16x8 al = *(const bf16x8*)(la + ks * 32);
#pragma unroll
    for (int ct = 0; ct < 16; ++ct) {
      bf16x8 bh = *(const bf16x8*)(wh + (ct * 16 + l4) * 256 + ks * 32 + g * 8);
      bf16x8 bl = *(const bf16x8*)(wl + (ct * 16 + l4) * 256 + ks * 32 + g * 8);
      acc[ct] = MFMA16(ah, bh, acc[ct]);
      acc[ct] = MFMA16(al, bh, acc[ct]);
      acc[ct] = MFMA16(ah, bl, acc[ct]);
    }
  }
  int orow = iblk * 64 + w * 16 + g * 4;
#pragma unroll
  for (int ct = 0; ct < 16; ++ct) {
    int c = ct * 16 + l4;
    float bsv = bias[c];
#pragma unroll
    for (int r = 0; r < 4; ++r) {
      float val = (acc[ct][r] + bsv) * scale;
      short h = f2bf(val);
      short lo = f2bf(val - bf2f(h));
      size_t off = ((size_t)(orow + r)) * 256 + c;
      ohi[off] = h;
      olo[off] = lo;
    }
  }
}

// ----------------------------- V projection --------------------------------
__global__ __launch_bounds__(256) void proj_v_k(
    const short* __restrict__ hn_hi, const short* __restrict__ wv_hi,
    const float* __restrict__ bv, short* __restrict__ vout) {
  int tid = threadIdx.x, w = tid >> 6, lane = tid & 63, l4 = lane & 15, g = lane >> 4;
  int jblk = blockIdx.x, cblk = blockIdx.y, b = blockIdx.z;
  int crow = cblk * 64 + w * 16 + l4;
  const short* ap = wv_hi + (size_t)crow * 256 + g * 8;
  f32x4 acc[4];
#pragma unroll
  for (int i = 0; i < 4; ++i) acc[i] = (f32x4){0.f, 0.f, 0.f, 0.f};
  for (int ks = 0; ks < 8; ++ks) {
    bf16x8 a = *(const bf16x8*)(ap + ks * 32);
#pragma unroll
    for (int jt = 0; jt < 4; ++jt) {
      bf16x8 bb = *(const bf16x8*)(hn_hi +
          ((size_t)(b * 4096 + jblk * 64 + jt * 16 + l4)) * 256 + ks * 32 + g * 8);
      acc[jt] = MFMA16(a, bb, acc[jt]);
    }
  }
#pragma unroll
  for (int jt = 0; jt < 4; ++jt) {
#pragma unroll
    for (int r = 0; r < 4; ++r) {
      int c = cblk * 64 + w * 16 + g * 4 + r;
      int j = jblk * 64 + jt * 16 + l4;
      float val = acc[jt][r] + bv[c];
      vout[((size_t)(b * 256 + c)) * 4096 + j] = f2bf(val);
    }
  }
}

// ------------------------------ flash attention v4 -------------------------
// 8 waves, 128 i-rows/block, 1 block/CU (grid 32x8 = 256).
// S: wave (wj = w&1, wi = w>>1) computes S[j = wj*16..+16][i = wi*32..+32]
//    (2 i-tiles). K-read per wave = 16 rows x 512B x 2 = 16KB (2x redundancy).
// Softmax: per-wave partial row-max -> LDS exchange across wj pair -> m/alpha
//    computed identically by both wj waves. P[128 i][32 j] bf16, 80B stride.
// PV: c-split 8-way, wave owns c in [w*32, w*32+32), V from global regs.
__global__ __launch_bounds__(512, 2) void flash4_k(
    const short* __restrict__ qhi, const short* __restrict__ qlo,
    const short* __restrict__ khi, const short* __restrict__ klo,
    const short* __restrict__ vv, const float* __restrict__ x,
    const short* __restrict__ wo_hi, const float* __restrict__ bo,
    float* __restrict__ out) {
  __shared__ short k_hi_s[2][8192];  // [dbuf][32 j][256 ch], row-XOR-swizzled
  __shared__ short k_lo_s[2][8192];
  __shared__ short p_s[128 * 40];    // [128 i][40 shorts] = 80B stride
  __shared__ __attribute__((aligned(16))) float xbuf[2][128];
  __shared__ __attribute__((aligned(16))) float albuf[128];
  __shared__ __attribute__((aligned(16))) float lsmbuf[128];
  __shared__ __attribute__((aligned(16))) float flagbuf[4];

  int tid = threadIdx.x, w = tid >> 6, lane = tid & 63, l4 = lane & 15, g = lane >> 4;
  int wj = w & 1, wi = w >> 1;
  int b = blockIdx.y, i0 = blockIdx.x * 128;
  size_t boff = (size_t)b * 1048576;
  const short* qh_p = qhi + boff;
  const short* ql_p = qlo + boff;
  const char* kh_g = (const char*)(khi + boff);
  const char* kl_g = (const char*)(klo + boff);
  const short* v_p = vv + boff;

  // Q fragments for this wave's 32 i-rows (B-operand: col i = l4)
  bf16x8 qh[2][8], ql[2][8];
#pragma unroll
  for (int it = 0; it < 2; ++it) {
    int qrow = i0 + wi * 32 + it * 16 + l4;
#pragma unroll
    for (int ks = 0; ks < 8; ++ks) {
      qh[it][ks] = *(const bf16x8*)(qh_p + (size_t)qrow * 256 + ks * 32 + g * 8);
      ql[it][ks] = *(const bf16x8*)(ql_p + (size_t)qrow * 256 + ks * 32 + g * 8);
    }
  }

  f32x4 oac[8][2];   // [i-tile 0..7][c-tile]; i = it8*16+g*4+r, c = w*32+ct*16+l4
#pragma unroll
  for (int it = 0; it < 8; ++it) {
    oac[it][0] = (f32x4){0.f, 0.f, 0.f, 0.f};
    oac[it][1] = (f32x4){0.f, 0.f, 0.f, 0.f};
  }
  float m0 = -1e30f, m1 = -1e30f, ls0 = 0.f, ls1 = 0.f;

  // K LDS read offsets (A-operand rows = wave's 16 j, swizzled by row&7=l4&7)
  int krow_b = (wj * 16 + l4) * 512;
  int sx = (l4 & 7) << 4;
  int colx[8];
#pragma unroll
  for (int ks = 0; ks < 8; ++ks) colx[ks] = (ks * 64 + g * 16) ^ sx;

  // staging: pre-swizzled per-thread global source offsets (LDS dest linear)
  int ksrc[2];
#pragma unroll
  for (int it = 0; it < 2; ++it) {
    int d = tid * 16 + it * 8192;
    int krow = d >> 9, kcol = d & 511;
    ksrc[it] = krow * 512 + (kcol ^ ((krow & 7) << 4));
  }

  char* khs = (char*)k_hi_s;
  char* kls = (char*)k_lo_s;
  char* ps = (char*)p_s;
  int cbase = w * 32;
  int prow0 = (wi * 32 + l4) * 80 + wj * 32 + g * 8;       // P-write it=0
  int prow1 = (wi * 32 + 16 + l4) * 80 + wj * 32 + g * 8;  // P-write it=1

  // prologue: stage K(0) into buffer 0; load V(0) regs
#pragma unroll
  for (int it = 0; it < 2; ++it) {
    int ldst = w * 1024 + it * 8192;  // wave-uniform base; HW adds lane*16
    async16(khs + ldst, kh_g + ksrc[it]);
    async16(kls + ldst, kl_g + ksrc[it]);
  }
  bf16x8 vreg[2];
#pragma unroll
  for (int ct = 0; ct < 2; ++ct)
    vreg[ct] = *(const bf16x8*)(v_p + (size_t)(cbase + ct * 16 + l4) * 4096 + g * 8);

  for (int js = 0; js < 128; ++js) {
    int cur = (js & 1) * 16384;
    __syncthreads();   // B1: K(js) staged (vmcnt drained); P(js-1) reads done
    if (js < 127) {
      int kgo = (js + 1) * 16384;
      int nxt = ((js + 1) & 1) * 16384;
#pragma unroll
      for (int it = 0; it < 2; ++it) {
        int ldst = nxt + w * 1024 + it * 8192;
        async16(khs + ldst, kh_g + kgo + ksrc[it]);
        async16(kls + ldst, kl_g + kgo + ksrc[it]);
      }
    }

    // S phase: wave's S[16 j][32 i] (2 i-tiles), 3-term bf16x2
    f32x4 sa0 = (f32x4){0.f, 0.f, 0.f, 0.f};
    f32x4 sa1 = (f32x4){0.f, 0.f, 0.f, 0.f};
    __builtin_amdgcn_s_setprio(1);
#pragma unroll
    for (int ks = 0; ks < 8; ++ks) {
      bf16x8 kh = *(const bf16x8*)(khs + cur + krow_b + colx[ks]);
      bf16x8 kl = *(const bf16x8*)(kls + cur + krow_b + colx[ks]);
      sa0 = MFMA16(kh, qh[0][ks], sa0);
      sa1 = MFMA16(kh, qh[1][ks], sa1);
      sa0 = MFMA16(kh, ql[0][ks], sa0);
      sa1 = MFMA16(kh, ql[1][ks], sa1);
      sa0 = MFMA16(kl, qh[0][ks], sa0);
      sa1 = MFMA16(kl, qh[1][ks], sa1);
    }
    __builtin_amdgcn_s_setprio(0);

    // partial row-max over this wave's 16 j (4 regs + 2 shfls across g)
    float pmax0 = fmaxf(fmaxf(sa0[0], sa0[1]), fmaxf(sa0[2], sa0[3]));
    float pmax1 = fmaxf(fmaxf(sa1[0], sa1[1]), fmaxf(sa1[2], sa1[3]));
    pmax0 = fmaxf(pmax0, __shfl_xor(pmax0, 16));
    pmax0 = fmaxf(pmax0, __shfl_xor(pmax0, 32));
    pmax1 = fmaxf(pmax1, __shfl_xor(pmax1, 16));
    pmax1 = fmaxf(pmax1, __shfl_xor(pmax1, 32));
    if (lane < 16) {
      xbuf[wj][wi * 32 + lane] = pmax0;
      xbuf[wj][wi * 32 + 16 + lane] = pmax1;
    }
    lgkm_barrier();    // B_mid: both wj halves' partial maxima visible

    pmax0 = fmaxf(pmax0, xbuf[wj ^ 1][wi * 32 + l4]);
    pmax1 = fmaxf(pmax1, xbuf[wj ^ 1][wi * 32 + 16 + l4]);
    // both wj waves compute identical m/alpha evolution (same pmax_tot)
    float alpha0 = 1.0f, alpha1 = 1.0f;
    bool upd = !__all((pmax0 <= m0 + 11.0f) && (pmax1 <= m1 + 11.0f));
    if (upd) {
      float mn0 = fmaxf(m0, pmax0), mn1 = fmaxf(m1, pmax1);
      alpha0 = exp2f(m0 - mn0);
      alpha1 = exp2f(m1 - mn1);
      ls0 *= alpha0;
      ls1 *= alpha1;
      m0 = mn0;
      m1 = mn1;
    }
    f32x4 e0, e1;
#pragma unroll
    for (int r = 0; r < 4; ++r) {
      e0[r] = exp2f(sa0[r] - m0);
      e1[r] = exp2f(sa1[r] - m1);
    }
    ls0 += e0[0] + e0[1] + e0[2] + e0[3];
    ls1 += e1[0] + e1[1] + e1[2] + e1[3];

    s16x4 pw0 = {f2bf(e0[0]), f2bf(e0[1]), f2bf(e0[2]), f2bf(e0[3])};
    s16x4 pw1 = {f2bf(e1[0]), f2bf(e1[1]), f2bf(e1[2]), f2bf(e1[3])};
    *(s16x4*)(ps + prow0) = pw0;
    *(s16x4*)(ps + prow1) = pw1;
    if (wj == 0 && lane < 16) {
      albuf[wi * 32 + lane] = alpha0;
      albuf[wi * 32 + 16 + lane] = alpha1;
    }
    if (wj == 0 && lane == 0) flagbuf[wi] = upd ? 1.f : 0.f;
    lgkm_barrier();    // B2: P/alpha/flag of js visible to all waves

    // PV: rescale then accumulate P(js) * V(js) for wave's 32 c x 128 i
    f32x4 fl = *(const f32x4*)(&flagbuf[0]);
    if (fl[0] + fl[1] + fl[2] + fl[3] > 0.f) {
#pragma unroll
      for (int it = 0; it < 8; ++it) {
        f32x4 av = *(const f32x4*)(&albuf[it * 16 + g * 4]);
#pragma unroll
        for (int r = 0; r < 4; ++r) {
          oac[it][0][r] *= av[r];
          oac[it][1][r] *= av[r];
        }
      }
    }
#pragma unroll
    for (int it = 0; it < 8; ++it) {
      bf16x8 pf = *(const bf16x8*)(ps + (it * 16 + l4) * 80 + g * 16);
      oac[it][0] = MFMA16(pf, vreg[0], oac[it][0]);
      oac[it][1] = MFMA16(pf, vreg[1], oac[it][1]);
    }
    // load V(js+1) regs (drained harmlessly at next B1)
    if (js < 127) {
#pragma unroll
      for (int ct = 0; ct < 2; ++ct)
        vreg[ct] = *(const bf16x8*)(v_p + (size_t)(cbase + ct * 16 + l4) * 4096 +
                                    (js + 1) * 32 + g * 8);
    }
  }

  // ---- epilogue: total lsum (g-shfls + wj exchange), 1/lsum, Wo*x ---------
  ls0 += __shfl_xor(ls0, 16);
  ls0 += __shfl_xor(ls0, 32);
  ls1 += __shfl_xor(ls1, 16);
  ls1 += __shfl_xor(ls1, 32);
  if (lane < 16) {
    xbuf[wj][wi * 32 + lane] = ls0;
    xbuf[wj][wi * 32 + 16 + lane] = ls1;
  }
  lgkm_barrier();
  float t0 = ls0 + xbuf[wj ^ 1][wi * 32 + l4];
  float t1 = ls1 + xbuf[wj ^ 1][wi * 32 + 16 + l4];
  if (wj == 0 && lane < 16) {
    lsmbuf[wi * 32 + l4] = 1.f / t0;
    lsmbuf[wi * 32 + 16 + l4] = 1.f / t1;
  }
  lgkm_barrier();
#pragma unroll
  for (int it = 0; it < 8; ++it) {
    f32x4 iv = *(const f32x4*)(&lsmbuf[it * 16 + g * 4]);
#pragma unroll
    for (int r = 0; r < 4; ++r) {
      oac[it][0][r] *= iv[r];
      oac[it][1][r] *= iv[r];
    }
  }
  // Wo * x accumulated straight into oac (A = x^T fragments, B = Wo rows)
  const float* xb = x + (size_t)b * 1048576;
  for (int ks = 0; ks < 8; ++ks) {
    bf16x8 bfr[2];
#pragma unroll
    for (int ct = 0; ct < 2; ++ct)
      bfr[ct] = *(const bf16x8*)(wo_hi + (cbase + ct * 16 + l4) * 256 + ks * 32 + g * 8);
#pragma unroll
    for (int it = 0; it < 8; ++it) {
      bf16x8 af;
#pragma unroll
      for (int e = 0; e < 8; ++e) {
        float xv = xb[(size_t)(ks * 32 + g * 8 + e) * 4096 + i0 + it * 16 + l4];
        af[e] = f2bf(xv);
      }
      oac[it][0] = MFMA16(af, bfr[0], oac[it][0]);
      oac[it][1] = MFMA16(af, bfr[1], oac[it][1]);
    }
  }
  float* ob = out + (size_t)b * 1048576;
#pragma unroll
  for (int ct = 0; ct < 2; ++ct) {
    float bov = bo[cbase + ct * 16 + l4];
#pragma unroll
    for (int it = 0; it < 8; ++it) {
      float* ad = ob + (size_t)(cbase + ct * 16 + l4) * 4096 + i0 + it * 16 + g * 4;
      f32x4 res;
#pragma unroll
      for (int r = 0; r < 4; ++r) res[r] = oac[it][ct][r] + bov;
      *(f32x4*)ad = res;
    }
  }
}

// ---------------------------------------------------------------------------
extern "C" void kernel_launch(void* const* d_in, const int* in_sizes, int n_in,
                              void* d_out, int out_size, void* d_ws, size_t ws_size,
                              hipStream_t stream) {
  (void)in_sizes; (void)n_in; (void)out_size; (void)ws_size;
  const float* x = (const float*)d_in[0];
  const float* gamma = (const float*)d_in[1];
  const float* beta = (const float*)d_in[2];
  const float* Wq = (const float*)d_in[3];
  const float* bq = (const float*)d_in[4];
  const float* Wk = (const float*)d_in[5];
  const float* bk = (const float*)d_in[6];
  const float* Wv = (const float*)d_in[7];
  const float* bv = (const float*)d_in[8];
  const float* Wo = (const float*)d_in[9];
  const float* bo = (const float*)d_in[10];
  float* out = (float*)d_out;
  char* ws = (char*)d_ws;

  const size_t MB16 = 16777216;  // 8*4096*256 bf16
  float* stats = (float*)(ws);                      // 2KB
  short* whi = (short*)(ws + 4096);                 // 4 * 64K shorts
  short* wlo = (short*)(ws + 4096 + 524288);
  char* base = ws + 4096 + 2 * 524288;
  short* hnhi = (short*)(base);
  short* hnlo = (short*)(base + MB16);
  short* qhi = (short*)(base + 2 * MB16);
  short* qlo = (short*)(base + 3 * MB16);
  short* khi = (short*)(base + 4 * MB16);
  short* klo = (short*)(base + 5 * MB16);
  short* vvp = (short*)(base + 6 * MB16);

  wsplit_k<<<dim3(1024), dim3(256), 0, stream>>>(Wq, Wk, Wv, Wo, whi, wlo);
  gn_stats_k<<<dim3(256), dim3(256), 0, stream>>>(x, stats);
  gn_apply_k<<<dim3(64, 4, 8), dim3(256), 0, stream>>>(x, gamma, beta, stats, hnhi, hnlo);
  proj_qk_k<<<dim3(64, 2, 8), dim3(256), 0, stream>>>(hnhi, hnlo, whi, wlo, bq, bk,
                                                      qhi, qlo, khi, klo);
  proj_v_k<<<dim3(64, 4, 8), dim3(256), 0, stream>>>(hnhi, whi + 2 * 65536, bv, vvp);
  flash4_k<<<dim3(32, 8), dim3(512), 0, stream>>>(qhi, qlo, khi, klo, vvp, x,
                                                  whi + 3 * 65536, bo, out);
}